// Round 1
// baseline (468.925 us; speedup 1.0000x reference)
//
#include <hip/hip_runtime.h>
#include <stdint.h>

// y[8192,4096] = x[8192,4096] @ W[4096,4096]^T + bias
// W from codebook[4096,8] gathered by indices[2M].
// R5: GEMM ported to the 256x256 8-phase counted-vmcnt structure
//     (T1 XCD swizzle + T2 LDS chunk-XOR swizzle + T3/T4 phased schedule
//      with vmcnt(4) held across barriers + T5 setprio around MFMA).
//     Prep kernel unchanged from R4 (verified).

#define M_DIM 8192
#define N_DIM 4096
#define K_DIM 4096
#define BM 256
#define BN 256
#define BK 64
#define NT (K_DIM / BK)                       // 64 K-tiles
#define NUM_W_BLOCKS 2097152                  // 4096*4096/8
#define W_WGS (NUM_W_BLOCKS / 256)            // 8192 WGs for W dequant
#define X_WGS ((M_DIM * K_DIM / 4) / 256)     // 32768 WGs, one float4/thread

typedef __attribute__((ext_vector_type(8))) __bf16 bf16x8;
typedef __attribute__((ext_vector_type(4))) float floatx4;
typedef __attribute__((ext_vector_type(2))) unsigned int uintx2;

// fp32 -> bf16 round-to-nearest-even (finite inputs)
__device__ __forceinline__ unsigned int f2bf(float f) {
    unsigned int u = __builtin_bit_cast(unsigned int, f);
    u += 0x7fffu + ((u >> 16) & 1u);
    return u >> 16;
}

// ------------- fused prep: W dequant-gather + x fp32->bf16 -------------
__global__ __launch_bounds__(256) void prep_kernel(
    const float* __restrict__ cb, const int* __restrict__ idx,
    uint4* __restrict__ W, const floatx4* __restrict__ x,
    uintx2* __restrict__ xb) {
    const int wg = blockIdx.x;
    if (wg < W_WGS) {
        const int b = wg * 256 + threadIdx.x;
        const int id = __builtin_nontemporal_load(idx + b);
        const float4* s = (const float4*)(cb + ((size_t)id << 3));
        const float4 a = s[0];
        const float4 c = s[1];
        uint4 o;
        o.x = f2bf(a.x) | (f2bf(a.y) << 16);
        o.y = f2bf(a.z) | (f2bf(a.w) << 16);
        o.z = f2bf(c.x) | (f2bf(c.y) << 16);
        o.w = f2bf(c.z) | (f2bf(c.w) << 16);
        W[b] = o;
    } else {
        const size_t t = (size_t)(wg - W_WGS) * 256 + threadIdx.x;
        const floatx4 a = __builtin_nontemporal_load(x + t);
        uintx2 o;
        o.x = f2bf(a.x) | (f2bf(a.y) << 16);
        o.y = f2bf(a.z) | (f2bf(a.w) << 16);
        xb[t] = o;
    }
}

// ---------------- async global -> LDS, 16B per lane ----------------
__device__ __forceinline__ void async_copy16(const __bf16* g, __bf16* s) {
    __builtin_amdgcn_global_load_lds(
        (const __attribute__((address_space(1))) unsigned int*)(uintptr_t)g,
        (__attribute__((address_space(3))) unsigned int*)(uintptr_t)s,
        16, 0, 0);
}

// Stage one unit = one operand k-half (256 rows x 32 bf16 = 16 KiB):
// 2 global_load_lds per thread (rows 0-127, rows 128-255).
// LDS dest is wave-uniform base + lane*16B (linear); swizzle is applied
// by pre-swizzling the per-lane GLOBAL source chunk (schunk).
#define STAGE(gsrc, arr, slotElems)                                        \
    do {                                                                   \
        async_copy16((gsrc), (arr) + (slotElems) + wave512);               \
        async_copy16((gsrc) + (size_t)128 * K_DIM,                         \
                     (arr) + (slotElems) + 4096 + wave512);                \
    } while (0)

// ---------------- GEMM: C[M][N] = A[M][K] * B[N][K]^T + bias ----------------
// 512 threads = 8 waves (2M x 4N); wave owns 128x64 output = acc[8][4] f32x4.
// LDS: per operand a 4-slot ring of 16KiB k-half units: slot = (t&1)*2 + kh.
// Per K-tile, 4 phases (kh x mh); each phase stages one unit and fences
// vmcnt(4) once per tile (2 units stay in flight across barriers).
__global__ __launch_bounds__(512, 2) void gemm_bt_kernel(
    const __bf16* __restrict__ A,   // [M][K] bf16
    const __bf16* __restrict__ B,   // [N][K] bf16
    const float* __restrict__ bias, // [N]
    float* __restrict__ C) {        // [M][N] fp32
    __shared__ __align__(16) __bf16 sA[4 * 8192];   // 64 KiB
    __shared__ __align__(16) __bf16 sB[4 * 8192];   // 64 KiB

    const int tid = threadIdx.x;
    const int wave = tid >> 6;
    const int lane = tid & 63;
    const int wr = wave >> 2;            // 0..1  (M half of tile)
    const int wc = wave & 3;             // 0..3  (N quarter of tile)

    // T1: bijective XCD swizzle; 512 WGs, 64 contiguous tiles per XCD,
    // m-fastest so one B panel (2 MiB) is L2-reused 32x.
    const int flat = blockIdx.x;
    const int swz = (flat & 7) * 64 + (flat >> 3);
    const int m0 = (swz & 31) * BM;
    const int n0 = (swz >> 5) * BN;

    // staging: thread t covers row = t>>2 (+128 for round 1), phys chunk t&3;
    // fetch logical chunk c = p ^ ((row>>1)&3)  (involution, row-bit invariant
    // under +16/+128 so one schunk serves all rounds/units).
    const int srow = tid >> 2;
    const int schunk = ((tid & 3) ^ ((srow >> 1) & 3)) << 3;
    const __bf16* gA = A + (size_t)(m0 + srow) * K_DIM + schunk;
    const __bf16* gB = B + (size_t)(n0 + srow) * K_DIM + schunk;
    const int wave512 = wave << 9;

    // fragment reads: lane holds X[row = base + fr][k = (lane>>4)*8 + j];
    // physical chunk = (lane>>4) ^ ((fr>>1)&3)  -> 16 lanes spread over all
    // 8 16B bank-slots (2-way = free).
    const int fr = lane & 15;
    const int roff = fr * 32 + (((lane >> 4) ^ ((fr >> 1) & 3)) << 3);
    const int aBase = wr * 4096 + roff;  // wr*128 rows * 32 elems
    const int bBase = wc * 2048 + roff;  // wc*64 rows * 32 elems

    floatx4 acc[8][4] = {};

    // ---- prologue: tile0 fully (4 units) + tile1 k-half0 (2 units) ----
    STAGE(gA, sA, 0);             // A kh0 t0 -> slot 0
    STAGE(gB, sB, 0);
    STAGE(gA + 32, sA, 8192);     // A kh1 t0 -> slot 1
    STAGE(gB + 32, sB, 8192);
    STAGE(gA + 64, sA, 16384);    // A kh0 t1 -> slot 2
    STAGE(gB + 64, sB, 16384);
    asm volatile("s_waitcnt vmcnt(4)" ::: "memory");  // tile0's 8 loads done
    __builtin_amdgcn_s_barrier();

    for (int t = 0; t < NT; ++t) {
        const int cs = (t & 1) ? 16384 : 0;   // this tile's kh0 slot (elems)
        const int ns = cs ^ 16384;            // next tile's kh0 slot
        const __bf16* sA0 = sA + cs;
        const __bf16* sA1 = sA + cs + 8192;
        const __bf16* sB0 = sB + cs;
        const __bf16* sB1 = sB + cs + 8192;

        bf16x8 af[4], bfr[4];

        // ---- P1: kh0 x mh0 ; stage A-kh1(t+1) (slot read-free since P4(t-1))
#pragma unroll
        for (int i = 0; i < 4; ++i)
            af[i] = *(const bf16x8*)(sA0 + aBase + i * 512);
#pragma unroll
        for (int j = 0; j < 4; ++j)
            bfr[j] = *(const bf16x8*)(sB0 + bBase + j * 512);
        if (t + 1 < NT) { STAGE(gA + (size_t)(t + 1) * 64 + 32, sA, ns + 8192); }
        __builtin_amdgcn_s_barrier();
        asm volatile("s_waitcnt lgkmcnt(0)" ::: "memory");
        __builtin_amdgcn_s_setprio(1);
#pragma unroll
        for (int i = 0; i < 4; ++i)
#pragma unroll
            for (int j = 0; j < 4; ++j)
                acc[i][j] = __builtin_amdgcn_mfma_f32_16x16x32_bf16(
                    af[i], bfr[j], acc[i][j], 0, 0, 0);
        __builtin_amdgcn_s_setprio(0);
        __builtin_amdgcn_s_barrier();

        // ---- P2: kh0 x mh1 ; stage B-kh1(t+1) (read-free since P3(t-1))
#pragma unroll
        for (int i = 0; i < 4; ++i)
            af[i] = *(const bf16x8*)(sA0 + aBase + 2048 + i * 512);
        if (t + 1 < NT) { STAGE(gB + (size_t)(t + 1) * 64 + 32, sB, ns + 8192); }
        __builtin_amdgcn_s_barrier();
        asm volatile("s_waitcnt lgkmcnt(0)" ::: "memory");
        __builtin_amdgcn_s_setprio(1);
#pragma unroll
        for (int i = 0; i < 4; ++i)
#pragma unroll
            for (int j = 0; j < 4; ++j)
                acc[i + 4][j] = __builtin_amdgcn_mfma_f32_16x16x32_bf16(
                    af[i], bfr[j], acc[i + 4][j], 0, 0, 0);
        __builtin_amdgcn_s_setprio(0);
        __builtin_amdgcn_s_barrier();

        // ---- P3: kh1 x mh0 ; stage A-kh0(t+2) (kh0 reads finished at P2)
#pragma unroll
        for (int i = 0; i < 4; ++i)
            af[i] = *(const bf16x8*)(sA1 + aBase + i * 512);
#pragma unroll
        for (int j = 0; j < 4; ++j)
            bfr[j] = *(const bf16x8*)(sB1 + bBase + j * 512);
        if (t + 2 < NT) { STAGE(gA + (size_t)(t + 2) * 64, sA, cs); }
        __builtin_amdgcn_s_barrier();
        asm volatile("s_waitcnt lgkmcnt(0)" ::: "memory");
        __builtin_amdgcn_s_setprio(1);
#pragma unroll
        for (int i = 0; i < 4; ++i)
#pragma unroll
            for (int j = 0; j < 4; ++j)
                acc[i][j] = __builtin_amdgcn_mfma_f32_16x16x32_bf16(
                    af[i], bfr[j], acc[i][j], 0, 0, 0);
        __builtin_amdgcn_s_setprio(0);
        __builtin_amdgcn_s_barrier();

        // ---- P4: kh1 x mh1 ; stage B-kh0(t+2) ; per-tile vmcnt fence
#pragma unroll
        for (int i = 0; i < 4; ++i)
            af[i] = *(const bf16x8*)(sA1 + aBase + 2048 + i * 512);
        if (t + 2 < NT) { STAGE(gB + (size_t)(t + 2) * 64, sB, cs); }
        __builtin_amdgcn_s_barrier();
        asm volatile("s_waitcnt lgkmcnt(0)" ::: "memory");
        __builtin_amdgcn_s_setprio(1);
#pragma unroll
        for (int i = 0; i < 4; ++i)
#pragma unroll
            for (int j = 0; j < 4; ++j)
                acc[i + 4][j] = __builtin_amdgcn_mfma_f32_16x16x32_bf16(
                    af[i], bfr[j], acc[i + 4][j], 0, 0, 0);
        __builtin_amdgcn_s_setprio(0);
        // tile t+1 fully staged; keep P3/P4's 4 loads (tile t+2 kh0) in
        // flight across the barrier. Tail (no t+2 staging): drain to 0.
        if (t < NT - 2)
            asm volatile("s_waitcnt vmcnt(4)" ::: "memory");
        else
            asm volatile("s_waitcnt vmcnt(0)" ::: "memory");
        __builtin_amdgcn_s_barrier();
    }

    // Epilogue. C/D layout: col = lane&15, row = (lane>>4)*4 + reg
    const int crow = (lane >> 4) * 4;
    const int ccol = lane & 15;
#pragma unroll
    for (int j = 0; j < 4; ++j) {
        const int n = n0 + wc * 64 + j * 16 + ccol;
        const float bv = bias[n];
#pragma unroll
        for (int i = 0; i < 8; ++i) {
            const int m = m0 + wr * 128 + i * 16 + crow;
            float* cp = C + (size_t)m * N_DIM + n;
#pragma unroll
            for (int r = 0; r < 4; ++r)
                __builtin_nontemporal_store(acc[i][j][r] + bv,
                                            cp + (size_t)r * N_DIM);
        }
    }
}

extern "C" void kernel_launch(void* const* d_in, const int* in_sizes, int n_in,
                              void* d_out, int out_size, void* d_ws, size_t ws_size,
                              hipStream_t stream) {
    const float* x    = (const float*)d_in[0];   // [4,2048,4096] fp32
    const float* cb   = (const float*)d_in[1];   // [4096,8] fp32
    const int*   idx  = (const int*)d_in[2];     // [2M]
    const float* bias = (const float*)d_in[3];   // [4096]
    float* out = (float*)d_out;                  // [4,2048,4096] fp32

    // workspace layout: W_bf16 (32 MB) | x_bf16 (64 MB)
    __bf16* Wb = (__bf16*)d_ws;
    __bf16* Xb = (__bf16*)((char*)d_ws + (size_t)N_DIM * K_DIM * sizeof(__bf16));

    prep_kernel<<<W_WGS + X_WGS, 256, 0, stream>>>(
        cb, idx, (uint4*)Wb, (const floatx4*)x, (uintx2*)Xb);

    dim3 grid(M_DIM / BM * (N_DIM / BN));  // 512 WGs, XCD-swizzled in-kernel
    gemm_bt_kernel<<<grid, 512, 0, stream>>>(Xb, Wb, bias, out);
}